// Round 18
// baseline (331.363 us; speedup 1.0000x reference)
//
#include <hip/hip_runtime.h>
#include <hip/hip_bf16.h>

// Problem constants (fixed by the reference file)
#define NC 8192      // n_clusters
#define SDIM 32
#define ADIM 4
#define XDIM 36      // SD + A
#define HDIM 64
#define MLP_BLOCKS 1024
#define CL_BLOCKS (NC / 4)   // 2048: one wave per cluster, 4 waves/block
// Workspace layout:
//   int   ctrl[16]   (ctrl[0]=done counter; gsum=(float*)(ctrl+4), 10 floats)
//                    zeroed by mlp_kernel block 0 each launch -> no memset node
//   float w_arr[n]
//   int   startx[NC], endx[NC]

typedef _Float16 half8 __attribute__((ext_vector_type(8)));
typedef _Float16 half4 __attribute__((ext_vector_type(4)));
typedef float f32x4 __attribute__((ext_vector_type(4)));

__device__ __forceinline__ float sigmoidf_(float t) {
    return 1.0f / (1.0f + __expf(-t));
}

__device__ __forceinline__ void gadd(float* p, float v) {
    __hip_atomic_fetch_add(p, v, __ATOMIC_RELAXED, __HIP_MEMORY_SCOPE_AGENT);
}

// ---- Node 1: bounds + ctrl-zero + LDS-staged MLP (r15 body, measured-best).
// Five mlp structures measured identical (64.6+-2us) -> body is not the cost;
// this round removes graph-node boundaries instead (4 nodes -> 2).
__global__ __launch_bounds__(256, 4) void mlp_kernel(
    const float* __restrict__ cell_state,
    const float* __restrict__ arch_state,
    const float* __restrict__ energy,
    const float* __restrict__ phi_local,
    const float* __restrict__ W1,
    const float* __restrict__ b1,
    const float* __restrict__ W2,
    const float* __restrict__ b2,
    const int*   __restrict__ seg,
    int* __restrict__ ctrl,
    int* __restrict__ startx,
    int* __restrict__ endx,
    float* __restrict__ w_out,
    int n)
{
    __shared__ _Float16 xs[256 * 40];   // 20 KB staged input image
    __shared__ half8 wpack[8 * 64];     // 4 KB packed W1^T/b1 fragments
    const int tid  = threadIdx.x;
    const int lane = tid & 63;
    const int l15  = lane & 15;
    const int lg   = lane >> 4;          // 0..3
    const int wv   = tid >> 6;           // wave id in block, 0..3

    // ---- zero done-counter + gsum for node 2 (block 0; no memset node) ----
    if (blockIdx.x == 0 && tid < 16) ctrl[tid] = 0;

    // ---- fused bounds phase (grid-stride; gap-fills empty clusters) ----
    for (int i = blockIdx.x * 256 + tid; i < n; i += gridDim.x * 256) {
        const int s = seg[i];
        if (i == 0) {
            startx[s] = 0;
            for (int c = 0; c < s; ++c) { startx[c] = 0; endx[c] = 0; }
        } else {
            const int sp = seg[i - 1];
            if (sp != s) {
                startx[s] = i;
                for (int c = sp + 1; c < s; ++c) { startx[c] = i; endx[c] = i; }
            }
        }
        if (i == n - 1) {
            endx[s] = n;
            for (int c = s + 1; c < NC; ++c) { startx[c] = n; endx[c] = n; }
        } else if (seg[i + 1] != s) {
            endx[s] = i + 1;
        }
    }

    // ---- parallel pack: wave wv packs fragments f = 2*wv, 2*wv+1 ----
    #pragma unroll
    for (int fo = 0; fo < 2; ++fo) {
        const int f  = 2 * wv + fo;      // f = nt*2 + s
        const int nt = f >> 1;
        const int s  = f & 1;
        half8 v = {};
        #pragma unroll
        for (int jj = 0; jj < 8; ++jj) {
            const int k = 32 * s + lg * 8 + jj;
            float wvv = 0.0f;
            if (k < XDIM)       wvv = W1[k * HDIM + 16 * nt + l15];
            else if (k == XDIM) wvv = b1[16 * nt + l15];   // bias row
            v[jj] = (_Float16)wvv;
        }
        wpack[f * 64 + lane] = v;
    }
    __syncthreads();

    half8 af[4][2];
    #pragma unroll
    for (int nt = 0; nt < 4; ++nt)
        #pragma unroll
        for (int s = 0; s < 2; ++s)
            af[nt][s] = wpack[(nt * 2 + s) * 64 + lane];

    float w2v[16];
    #pragma unroll
    for (int nt = 0; nt < 4; ++nt)
        #pragma unroll
        for (int q = 0; q < 4; ++q)
            w2v[nt * 4 + q] = W2[16 * nt + lg * 4 + q];
    const float sb2 = b2[0];

    const float4* cell4 = reinterpret_cast<const float4*>(cell_state);
    const float4* arch4 = reinterpret_cast<const float4*>(arch_state);

    #pragma unroll 1
    for (int cb = blockIdx.x * 256; cb < n; cb += gridDim.x * 256) {
        __syncthreads();

        // ---- stage 256 cells: LINEAR float4 loads, one-time f32->fp16 ----
        #pragma unroll
        for (int uu = 0; uu < 8; ++uu) {
            const int u   = uu * 256 + tid;
            const int row = u >> 3;
            const int c4  = u & 7;
            float4 v = {0.f, 0.f, 0.f, 0.f};
            if (cb + row < n) v = cell4[(size_t)cb * 8 + u];
            half4 h;
            h[0] = (_Float16)v.x; h[1] = (_Float16)v.y;
            h[2] = (_Float16)v.z; h[3] = (_Float16)v.w;
            *reinterpret_cast<half4*>(&xs[row * 40 + c4 * 4]) = h;
        }
        {
            const int row = tid;
            float4 a = {0.f, 0.f, 0.f, 0.f};
            if (cb + row < n) a = arch4[cb + row];
            half4 h;
            h[0] = (_Float16)a.x; h[1] = (_Float16)a.y;
            h[2] = (_Float16)a.z; h[3] = (_Float16)a.w;
            *reinterpret_cast<half4*>(&xs[row * 40 + 32]) = h;
            half4 hb;
            hb[0] = (_Float16)1.0f; hb[1] = (_Float16)0.0f;
            hb[2] = (_Float16)0.0f; hb[3] = (_Float16)0.0f;
            *reinterpret_cast<half4*>(&xs[row * 40 + 36]) = hb;
        }
        __syncthreads();

        // ---- compute: wave wv owns local rows wv*64..+63 ----
        float acc = 0.0f;
        #pragma unroll
        for (int t = 0; t < 4; ++t) {
            const int r = wv * 64 + 16 * t + l15;
            const half8 x0 = *reinterpret_cast<const half8*>(&xs[r * 40 + lg * 8]);
            half8 x1 = {};
            if (lg == 0)
                x1 = *reinterpret_cast<const half8*>(&xs[r * 40 + 32]);

            float pq = 0.0f;
            #pragma unroll
            for (int nt = 0; nt < 4; ++nt) {
                f32x4 cc = f32x4{0.f, 0.f, 0.f, 0.f};
                cc = __builtin_amdgcn_mfma_f32_16x16x32_f16(af[nt][0], x0, cc, 0, 0, 0);
                cc = __builtin_amdgcn_mfma_f32_16x16x32_f16(af[nt][1], x1, cc, 0, 0, 0);
                #pragma unroll
                for (int q = 0; q < 4; ++q)
                    pq = __builtin_fmaf(fmaxf(cc[q], 0.0f), w2v[nt * 4 + q], pq);
            }
            pq += __shfl_xor(pq, 16);
            pq += __shfl_xor(pq, 32);
            if (lg == t) acc = pq;
        }
        const float base = sigmoidf_(acc + sb2);

        const int gid = cb + wv * 64 + lane;
        if (gid < n) {
            const float ep = energy[gid] * phi_local[gid];
            const float imp = fminf(fmaxf(base * ep, 0.01f), 1.0f);
            w_out[gid] = imp * ep;
        }
    }
}

// ---- Node 2: cluster + last-block finalize (no spin; last arriver works) ----
__global__ __launch_bounds__(256) void cluster_kernel(
    const float* __restrict__ arch_state,
    const float* __restrict__ w_arr,
    const int*   __restrict__ startx,
    const int*   __restrict__ endx,
    const float* __restrict__ Wc1,
    const float* __restrict__ bc1,
    const float* __restrict__ Wc2,
    const float* __restrict__ bc2,
    int* __restrict__ ctrl,
    float* __restrict__ out)
{
    __shared__ float red[4][10];
    const int tid  = threadIdx.x;
    const int lane = tid & 63;
    const int wv   = tid >> 6;
    const int c = blockIdx.x * 4 + wv;
    const int s0 = startx[c];
    const int e0 = endx[c];
    float* gsum = (float*)(ctrl + 4);

    float pw = 0.0f;
    float pa0 = 0.f, pa1 = 0.f, pa2 = 0.f, pa3 = 0.f;
    float pw0 = 0.f, pw1 = 0.f, pw2 = 0.f, pw3 = 0.f;
    float pq0 = 0.f, pq1 = 0.f, pq2 = 0.f, pq3 = 0.f;
    const float4* arch4 = reinterpret_cast<const float4*>(arch_state);

    int i = s0 + lane;
    bool vcur = i < e0;
    float4 ac = {}; float wcur = 0.0f;
    if (vcur) { ac = arch4[i]; wcur = w_arr[i]; }
    while (vcur) {
        const int j = i + 64;
        const bool vnext = j < e0;
        float4 an = {}; float wnext = 0.0f;
        if (vnext) { an = arch4[j]; wnext = w_arr[j]; }   // prefetch next
        pw += wcur;
        pa0 += ac.x; pa1 += ac.y; pa2 += ac.z; pa3 += ac.w;
        pw0 = __builtin_fmaf(wcur, ac.x, pw0); pw1 = __builtin_fmaf(wcur, ac.y, pw1);
        pw2 = __builtin_fmaf(wcur, ac.z, pw2); pw3 = __builtin_fmaf(wcur, ac.w, pw3);
        pq0 = __builtin_fmaf(ac.x, ac.x, pq0); pq1 = __builtin_fmaf(ac.y, ac.y, pq1);
        pq2 = __builtin_fmaf(ac.z, ac.z, pq2); pq3 = __builtin_fmaf(ac.w, ac.w, pq3);
        i = j; vcur = vnext; ac = an; wcur = wnext;
    }
#define RED13(F) F(pw) F(pa0) F(pa1) F(pa2) F(pa3) \
                 F(pw0) F(pw1) F(pw2) F(pw3) F(pq0) F(pq1) F(pq2) F(pq3)
#define BFLY(V) V += __shfl_xor(V, off_);
    #pragma unroll
    for (int off_ = 1; off_ < 64; off_ <<= 1) { RED13(BFLY) }

    const float cnt = (float)(e0 - s0);
    const float safe_cnt = fmaxf(cnt, 1.0f);
    const float wsum = pw;

    float agg[4];
    if (wsum > 0.0f) {
        const float inv = 1.0f / fmaxf(wsum, 1e-30f);
        agg[0] = pw0 * inv; agg[1] = pw1 * inv;
        agg[2] = pw2 * inv; agg[3] = pw3 * inv;
    } else {
        const float inv = 1.0f / safe_cnt;
        agg[0] = pa0 * inv; agg[1] = pa1 * inv;
        agg[2] = pa2 * inv; agg[3] = pa3 * inv;
    }

    const float sA[4]  = { pa0, pa1, pa2, pa3 };
    const float sA2[4] = { pq0, pq1, pq2, pq3 };
    float sq = 0.0f;
    #pragma unroll
    for (int d = 0; d < 4; ++d) {
        const float mean = sA[d] / safe_cnt;
        const float s2 = sA2[d] - 2.0f * mean * sA[d] + cnt * mean * mean;
        sq += fmaxf(s2, 0.0f);
    }
    const float var = (cnt >= 2.0f) ? (sq * 0.25f) / fmaxf(cnt - 1.0f, 1.0f) : 0.0f;
    const float phi_c = 1.0f - fminf(1.0f, var * 2.0f);
    const float coh = 1.0f - var;

    const float feats[7] = { agg[0], agg[1], agg[2], agg[3],
                             phi_c, coh, fminf(1.0f, cnt * 0.05f) };
    float t = bc2[0];
    #pragma unroll
    for (int j = 0; j < 32; ++j) {
        float hj = bc1[j];
        #pragma unroll
        for (int k = 0; k < 7; ++k)
            hj = __builtin_fmaf(feats[k], Wc1[k * 32 + j], hj);
        t += fmaxf(hj, 0.0f) * Wc2[j];
    }
    const float basec = sigmoidf_(t);
    const float impc = fminf(fmaxf(basec * phi_c, 0.01f), 1.0f);
    const bool valid = cnt > 0.0f;
    const float wc = valid ? impc * cnt : 0.0f;
    const float vf = valid ? 1.0f : 0.0f;

    if (lane == 0) {
        out[c * 4 + 0] = agg[0]; out[c * 4 + 1] = agg[1];
        out[c * 4 + 2] = agg[2]; out[c * 4 + 3] = agg[3];
        out[NC * 4 + c] = phi_c;
        out[NC * 5 + c] = coh;
        // per-wave global partials into LDS
        red[wv][0] = wc;
        red[wv][1] = vf;
        #pragma unroll
        for (int d = 0; d < 4; ++d) red[wv][2 + d] = wc * agg[d];
        #pragma unroll
        for (int d = 0; d < 4; ++d) red[wv][6 + d] = vf * agg[d];
    }
    __syncthreads();

    // thread 0: block partials -> global atomics, then done-counter;
    // the LAST block to arrive computes global_archetype (no spinning).
    if (tid == 0) {
        #pragma unroll
        for (int k = 0; k < 10; ++k) {
            const float v = red[0][k] + red[1][k] + red[2][k] + red[3][k];
            gadd(&gsum[k], v);
        }
        const int old = __hip_atomic_fetch_add(&ctrl[0], 1, __ATOMIC_ACQ_REL,
                                               __HIP_MEMORY_SCOPE_AGENT);
        if (old == CL_BLOCKS - 1) {
            float g[10];
            #pragma unroll
            for (int k = 0; k < 10; ++k)
                g[k] = __hip_atomic_load(&gsum[k], __ATOMIC_RELAXED,
                                         __HIP_MEMORY_SCOPE_AGENT);
            const float wcs = g[0];
            const float nv = fmaxf(g[1], 1.0f);
            #pragma unroll
            for (int d = 0; d < 4; ++d) {
                out[NC * 6 + d] = (wcs > 0.0f) ? g[2 + d] / fmaxf(wcs, 1e-30f)
                                               : g[6 + d] / nv;
            }
        }
    }
}

extern "C" void kernel_launch(void* const* d_in, const int* in_sizes, int n_in,
                              void* d_out, int out_size, void* d_ws, size_t ws_size,
                              hipStream_t stream) {
    const float* cell_state = (const float*)d_in[0];
    const float* arch_state = (const float*)d_in[1];
    const float* energy     = (const float*)d_in[2];
    const float* phi_local  = (const float*)d_in[3];
    const float* W1  = (const float*)d_in[4];
    const float* b1  = (const float*)d_in[5];
    const float* W2  = (const float*)d_in[6];
    const float* b2  = (const float*)d_in[7];
    const float* Wc1 = (const float*)d_in[8];
    const float* bc1 = (const float*)d_in[9];
    const float* Wc2 = (const float*)d_in[10];
    const float* bc2 = (const float*)d_in[11];
    const int* seg   = (const int*)d_in[12];

    const int n = in_sizes[2];  // energy is [N]
    float* out = (float*)d_out;

    int* ctrl    = (int*)d_ws;                    // 16 ints
    float* w_arr = (float*)(ctrl + 16);           // n floats
    int* startx  = (int*)(w_arr + n);             // NC ints
    int* endx    = startx + NC;                   // NC ints

    mlp_kernel<<<MLP_BLOCKS, 256, 0, stream>>>(cell_state, arch_state, energy,
                                               phi_local, W1, b1, W2, b2, seg,
                                               ctrl, startx, endx, w_arr, n);
    cluster_kernel<<<CL_BLOCKS, 256, 0, stream>>>(arch_state, w_arr, startx,
                                                  endx, Wc1, bc1, Wc2, bc2,
                                                  ctrl, out);
}

// Round 19
// 328.019 us; speedup vs baseline: 1.0102x; 1.0102x over previous
//
#include <hip/hip_runtime.h>
#include <hip/hip_bf16.h>

// Problem constants (fixed by the reference file)
#define NC 8192      // n_clusters
#define SDIM 32
#define ADIM 4
#define XDIM 36      // SD + A
#define HDIM 64
#define MLP_BLOCKS 1024
#define CL_BLOCKS (NC / 4)   // 2048 blocks, one wave per cluster
// Workspace layout:
//   int   ctrl[16]   (ctrl[0]=done counter; gsum=(float*)(ctrl+4), 10 floats)
//                    zeroed by mlp_kernel block 0 -> no memset node
//   float w_arr[n]
//   int   startx[NC], endx[NC]

typedef _Float16 half8 __attribute__((ext_vector_type(8)));
typedef _Float16 half4 __attribute__((ext_vector_type(4)));
typedef float f32x4 __attribute__((ext_vector_type(4)));

__device__ __forceinline__ float sigmoidf_(float t) {
    return 1.0f / (1.0f + __expf(-t));
}

// RELAXED-only device atomics. r18 lesson: ONE ACQ_REL agent atomic per block
// turned a <10us kernel into 296us (L2 writeback/invalidate storms). Ordering
// for the last-block finalize is done with an explicit vmcnt fence instead.
__device__ __forceinline__ void gadd(float* p, float v) {
    __hip_atomic_fetch_add(p, v, __ATOMIC_RELAXED, __HIP_MEMORY_SCOPE_AGENT);
}

// ---- Node 1: ctrl-zero + bounds + LDS-staged MLP (r15 body, measured-best) ----
__global__ __launch_bounds__(256, 4) void mlp_kernel(
    const float* __restrict__ cell_state,
    const float* __restrict__ arch_state,
    const float* __restrict__ energy,
    const float* __restrict__ phi_local,
    const float* __restrict__ W1,
    const float* __restrict__ b1,
    const float* __restrict__ W2,
    const float* __restrict__ b2,
    const int*   __restrict__ seg,
    int* __restrict__ ctrl,
    int* __restrict__ startx,
    int* __restrict__ endx,
    float* __restrict__ w_out,
    int n)
{
    __shared__ _Float16 xs[256 * 40];   // 20 KB staged input image
    __shared__ half8 wpack[8 * 64];     // 4 KB packed W1^T/b1 fragments
    const int tid  = threadIdx.x;
    const int lane = tid & 63;
    const int l15  = lane & 15;
    const int lg   = lane >> 4;          // 0..3
    const int wv   = tid >> 6;           // wave id in block, 0..3

    // zero done-counter + gsum for node 2 (plain stores; graph orders nodes)
    if (blockIdx.x == 0 && tid < 16) ctrl[tid] = 0;

    // ---- fused bounds phase (grid-stride; gap-fills empty clusters) ----
    for (int i = blockIdx.x * 256 + tid; i < n; i += gridDim.x * 256) {
        const int s = seg[i];
        if (i == 0) {
            startx[s] = 0;
            for (int c = 0; c < s; ++c) { startx[c] = 0; endx[c] = 0; }
        } else {
            const int sp = seg[i - 1];
            if (sp != s) {
                startx[s] = i;
                for (int c = sp + 1; c < s; ++c) { startx[c] = i; endx[c] = i; }
            }
        }
        if (i == n - 1) {
            endx[s] = n;
            for (int c = s + 1; c < NC; ++c) { startx[c] = n; endx[c] = n; }
        } else if (seg[i + 1] != s) {
            endx[s] = i + 1;
        }
    }

    // ---- parallel pack: wave wv packs fragments f = 2*wv, 2*wv+1 ----
    #pragma unroll
    for (int fo = 0; fo < 2; ++fo) {
        const int f  = 2 * wv + fo;      // f = nt*2 + s
        const int nt = f >> 1;
        const int s  = f & 1;
        half8 v = {};
        #pragma unroll
        for (int jj = 0; jj < 8; ++jj) {
            const int k = 32 * s + lg * 8 + jj;
            float wvv = 0.0f;
            if (k < XDIM)       wvv = W1[k * HDIM + 16 * nt + l15];
            else if (k == XDIM) wvv = b1[16 * nt + l15];   // bias row
            v[jj] = (_Float16)wvv;
        }
        wpack[f * 64 + lane] = v;
    }
    __syncthreads();

    half8 af[4][2];
    #pragma unroll
    for (int nt = 0; nt < 4; ++nt)
        #pragma unroll
        for (int s = 0; s < 2; ++s)
            af[nt][s] = wpack[(nt * 2 + s) * 64 + lane];

    float w2v[16];
    #pragma unroll
    for (int nt = 0; nt < 4; ++nt)
        #pragma unroll
        for (int q = 0; q < 4; ++q)
            w2v[nt * 4 + q] = W2[16 * nt + lg * 4 + q];
    const float sb2 = b2[0];

    const float4* cell4 = reinterpret_cast<const float4*>(cell_state);
    const float4* arch4 = reinterpret_cast<const float4*>(arch_state);

    #pragma unroll 1
    for (int cb = blockIdx.x * 256; cb < n; cb += gridDim.x * 256) {
        __syncthreads();

        // ---- stage 256 cells: LINEAR float4 loads, one-time f32->fp16 ----
        #pragma unroll
        for (int uu = 0; uu < 8; ++uu) {
            const int u   = uu * 256 + tid;
            const int row = u >> 3;
            const int c4  = u & 7;
            float4 v = {0.f, 0.f, 0.f, 0.f};
            if (cb + row < n) v = cell4[(size_t)cb * 8 + u];
            half4 h;
            h[0] = (_Float16)v.x; h[1] = (_Float16)v.y;
            h[2] = (_Float16)v.z; h[3] = (_Float16)v.w;
            *reinterpret_cast<half4*>(&xs[row * 40 + c4 * 4]) = h;
        }
        {
            const int row = tid;
            float4 a = {0.f, 0.f, 0.f, 0.f};
            if (cb + row < n) a = arch4[cb + row];
            half4 h;
            h[0] = (_Float16)a.x; h[1] = (_Float16)a.y;
            h[2] = (_Float16)a.z; h[3] = (_Float16)a.w;
            *reinterpret_cast<half4*>(&xs[row * 40 + 32]) = h;
            half4 hb;
            hb[0] = (_Float16)1.0f; hb[1] = (_Float16)0.0f;
            hb[2] = (_Float16)0.0f; hb[3] = (_Float16)0.0f;
            *reinterpret_cast<half4*>(&xs[row * 40 + 36]) = hb;
        }
        __syncthreads();

        // ---- compute: wave wv owns local rows wv*64..+63 ----
        float acc = 0.0f;
        #pragma unroll
        for (int t = 0; t < 4; ++t) {
            const int r = wv * 64 + 16 * t + l15;
            const half8 x0 = *reinterpret_cast<const half8*>(&xs[r * 40 + lg * 8]);
            half8 x1 = {};
            if (lg == 0)
                x1 = *reinterpret_cast<const half8*>(&xs[r * 40 + 32]);

            float pq = 0.0f;
            #pragma unroll
            for (int nt = 0; nt < 4; ++nt) {
                f32x4 cc = f32x4{0.f, 0.f, 0.f, 0.f};
                cc = __builtin_amdgcn_mfma_f32_16x16x32_f16(af[nt][0], x0, cc, 0, 0, 0);
                cc = __builtin_amdgcn_mfma_f32_16x16x32_f16(af[nt][1], x1, cc, 0, 0, 0);
                #pragma unroll
                for (int q = 0; q < 4; ++q)
                    pq = __builtin_fmaf(fmaxf(cc[q], 0.0f), w2v[nt * 4 + q], pq);
            }
            pq += __shfl_xor(pq, 16);
            pq += __shfl_xor(pq, 32);
            if (lg == t) acc = pq;
        }
        const float base = sigmoidf_(acc + sb2);

        const int gid = cb + wv * 64 + lane;
        if (gid < n) {
            const float ep = energy[gid] * phi_local[gid];
            const float imp = fminf(fmaxf(base * ep, 0.01f), 1.0f);
            w_out[gid] = imp * ep;
        }
    }
}

// ---- Node 2: cluster + last-block finalize, RELAXED atomics only ----
__global__ __launch_bounds__(256) void cluster_kernel(
    const float* __restrict__ arch_state,
    const float* __restrict__ w_arr,
    const int*   __restrict__ startx,
    const int*   __restrict__ endx,
    const float* __restrict__ Wc1,
    const float* __restrict__ bc1,
    const float* __restrict__ Wc2,
    const float* __restrict__ bc2,
    int* __restrict__ ctrl,
    float* __restrict__ out)
{
    __shared__ float red[4][10];
    const int tid  = threadIdx.x;
    const int lane = tid & 63;
    const int wv   = tid >> 6;
    const int c = blockIdx.x * 4 + wv;
    const int s0 = startx[c];
    const int e0 = endx[c];
    float* gsum = (float*)(ctrl + 4);

    float pw = 0.0f;
    float pa0 = 0.f, pa1 = 0.f, pa2 = 0.f, pa3 = 0.f;
    float pw0 = 0.f, pw1 = 0.f, pw2 = 0.f, pw3 = 0.f;
    float pq0 = 0.f, pq1 = 0.f, pq2 = 0.f, pq3 = 0.f;
    const float4* arch4 = reinterpret_cast<const float4*>(arch_state);

    int i = s0 + lane;
    bool vcur = i < e0;
    float4 ac = {}; float wcur = 0.0f;
    if (vcur) { ac = arch4[i]; wcur = w_arr[i]; }
    while (vcur) {
        const int j = i + 64;
        const bool vnext = j < e0;
        float4 an = {}; float wnext = 0.0f;
        if (vnext) { an = arch4[j]; wnext = w_arr[j]; }   // prefetch next
        pw += wcur;
        pa0 += ac.x; pa1 += ac.y; pa2 += ac.z; pa3 += ac.w;
        pw0 = __builtin_fmaf(wcur, ac.x, pw0); pw1 = __builtin_fmaf(wcur, ac.y, pw1);
        pw2 = __builtin_fmaf(wcur, ac.z, pw2); pw3 = __builtin_fmaf(wcur, ac.w, pw3);
        pq0 = __builtin_fmaf(ac.x, ac.x, pq0); pq1 = __builtin_fmaf(ac.y, ac.y, pq1);
        pq2 = __builtin_fmaf(ac.z, ac.z, pq2); pq3 = __builtin_fmaf(ac.w, ac.w, pq3);
        i = j; vcur = vnext; ac = an; wcur = wnext;
    }
#define RED13(F) F(pw) F(pa0) F(pa1) F(pa2) F(pa3) \
                 F(pw0) F(pw1) F(pw2) F(pw3) F(pq0) F(pq1) F(pq2) F(pq3)
#define BFLY(V) V += __shfl_xor(V, off_);
    #pragma unroll
    for (int off_ = 1; off_ < 64; off_ <<= 1) { RED13(BFLY) }

    const float cnt = (float)(e0 - s0);
    const float safe_cnt = fmaxf(cnt, 1.0f);
    const float wsum = pw;

    float agg[4];
    if (wsum > 0.0f) {
        const float inv = 1.0f / fmaxf(wsum, 1e-30f);
        agg[0] = pw0 * inv; agg[1] = pw1 * inv;
        agg[2] = pw2 * inv; agg[3] = pw3 * inv;
    } else {
        const float inv = 1.0f / safe_cnt;
        agg[0] = pa0 * inv; agg[1] = pa1 * inv;
        agg[2] = pa2 * inv; agg[3] = pa3 * inv;
    }

    const float sA[4]  = { pa0, pa1, pa2, pa3 };
    const float sA2[4] = { pq0, pq1, pq2, pq3 };
    float sq = 0.0f;
    #pragma unroll
    for (int d = 0; d < 4; ++d) {
        const float mean = sA[d] / safe_cnt;
        const float s2 = sA2[d] - 2.0f * mean * sA[d] + cnt * mean * mean;
        sq += fmaxf(s2, 0.0f);
    }
    const float var = (cnt >= 2.0f) ? (sq * 0.25f) / fmaxf(cnt - 1.0f, 1.0f) : 0.0f;
    const float phi_c = 1.0f - fminf(1.0f, var * 2.0f);
    const float coh = 1.0f - var;

    const float feats[7] = { agg[0], agg[1], agg[2], agg[3],
                             phi_c, coh, fminf(1.0f, cnt * 0.05f) };
    float t = bc2[0];
    #pragma unroll
    for (int j = 0; j < 32; ++j) {
        float hj = bc1[j];
        #pragma unroll
        for (int k = 0; k < 7; ++k)
            hj = __builtin_fmaf(feats[k], Wc1[k * 32 + j], hj);
        t += fmaxf(hj, 0.0f) * Wc2[j];
    }
    const float basec = sigmoidf_(t);
    const float impc = fminf(fmaxf(basec * phi_c, 0.01f), 1.0f);
    const bool valid = cnt > 0.0f;
    const float wc = valid ? impc * cnt : 0.0f;
    const float vf = valid ? 1.0f : 0.0f;

    if (lane == 0) {
        out[c * 4 + 0] = agg[0]; out[c * 4 + 1] = agg[1];
        out[c * 4 + 2] = agg[2]; out[c * 4 + 3] = agg[3];
        out[NC * 4 + c] = phi_c;
        out[NC * 5 + c] = coh;
        red[wv][0] = wc;
        red[wv][1] = vf;
        #pragma unroll
        for (int d = 0; d < 4; ++d) red[wv][2 + d] = wc * agg[d];
        #pragma unroll
        for (int d = 0; d < 4; ++d) red[wv][6 + d] = vf * agg[d];
    }
    __syncthreads();

    // thread 0: block partials -> RELAXED global fp32 atomics; vmcnt fence
    // guarantees the adds reached the coherence point BEFORE the relaxed
    // done-counter increment issues. Last block re-reads gsum via RMW
    // (fetch_add 0.0f -> served at coherence point, no stale cache).
    if (tid == 0) {
        #pragma unroll
        for (int k = 0; k < 10; ++k) {
            const float v = red[0][k] + red[1][k] + red[2][k] + red[3][k];
            gadd(&gsum[k], v);
        }
        asm volatile("s_waitcnt vmcnt(0)" ::: "memory");
        const int old = __hip_atomic_fetch_add(&ctrl[0], 1, __ATOMIC_RELAXED,
                                               __HIP_MEMORY_SCOPE_AGENT);
        if (old == CL_BLOCKS - 1) {
            float g[10];
            #pragma unroll
            for (int k = 0; k < 10; ++k)
                g[k] = __hip_atomic_fetch_add(&gsum[k], 0.0f, __ATOMIC_RELAXED,
                                              __HIP_MEMORY_SCOPE_AGENT);
            const float wcs = g[0];
            const float nv = fmaxf(g[1], 1.0f);
            #pragma unroll
            for (int d = 0; d < 4; ++d) {
                out[NC * 6 + d] = (wcs > 0.0f) ? g[2 + d] / fmaxf(wcs, 1e-30f)
                                               : g[6 + d] / nv;
            }
        }
    }
}

extern "C" void kernel_launch(void* const* d_in, const int* in_sizes, int n_in,
                              void* d_out, int out_size, void* d_ws, size_t ws_size,
                              hipStream_t stream) {
    const float* cell_state = (const float*)d_in[0];
    const float* arch_state = (const float*)d_in[1];
    const float* energy     = (const float*)d_in[2];
    const float* phi_local  = (const float*)d_in[3];
    const float* W1  = (const float*)d_in[4];
    const float* b1  = (const float*)d_in[5];
    const float* W2  = (const float*)d_in[6];
    const float* b2  = (const float*)d_in[7];
    const float* Wc1 = (const float*)d_in[8];
    const float* bc1 = (const float*)d_in[9];
    const float* Wc2 = (const float*)d_in[10];
    const float* bc2 = (const float*)d_in[11];
    const int* seg   = (const int*)d_in[12];

    const int n = in_sizes[2];  // energy is [N]
    float* out = (float*)d_out;

    int* ctrl    = (int*)d_ws;                    // 16 ints
    float* w_arr = (float*)(ctrl + 16);           // n floats
    int* startx  = (int*)(w_arr + n);             // NC ints
    int* endx    = startx + NC;                   // NC ints

    mlp_kernel<<<MLP_BLOCKS, 256, 0, stream>>>(cell_state, arch_state, energy,
                                               phi_local, W1, b1, W2, b2, seg,
                                               ctrl, startx, endx, w_arr, n);
    cluster_kernel<<<CL_BLOCKS, 256, 0, stream>>>(arch_state, w_arr, startx,
                                                  endx, Wc1, bc1, Wc2, bc2,
                                                  ctrl, out);
}

// Round 20
// 63.436 us; speedup vs baseline: 5.2236x; 5.1709x over previous
//
#include <hip/hip_runtime.h>
#include <hip/hip_bf16.h>

// Problem constants (fixed by the reference file)
#define NC 8192      // n_clusters
#define SDIM 32
#define ADIM 4
#define XDIM 36      // SD + A
#define HDIM 64
#define MLP_BLOCKS 1024
// Workspace layout:
//   float w_arr[n]                    (cell weights from MLP)
//   int   startx[NC], endx[NC]        (cluster ranges; gap-filled -> NO memset)
//   float ws2[10*NC]                  (per-cluster global partials, plain stores)

typedef _Float16 half8 __attribute__((ext_vector_type(8)));
typedef _Float16 half4 __attribute__((ext_vector_type(4)));
typedef float f32x4 __attribute__((ext_vector_type(4)));

__device__ __forceinline__ float sigmoidf_(float t) {
    return 1.0f / (1.0f + __expf(-t));
}

// ---- cluster range discovery; gap-fills empty clusters ----
__global__ __launch_bounds__(256) void bounds_kernel(
    const int* __restrict__ seg, int* __restrict__ startx,
    int* __restrict__ endx, int n)
{
    const int i = blockIdx.x * 256 + threadIdx.x;
    if (i >= n) return;
    const int s = seg[i];
    if (i == 0) {
        startx[s] = 0;
        for (int c = 0; c < s; ++c) { startx[c] = 0; endx[c] = 0; }
    } else {
        const int sp = seg[i - 1];
        if (sp != s) {
            startx[s] = i;
            for (int c = sp + 1; c < s; ++c) { startx[c] = i; endx[c] = i; }
        }
    }
    if (i == n - 1) {
        endx[s] = n;
        for (int c = s + 1; c < NC; ++c) { startx[c] = n; endx[c] = n; }
    } else if (seg[i + 1] != s) {
        endx[s] = i + 1;
    }
}

// ---- FREE-RUNNING-WAVE staged MLP: zero block barriers in the main loop ----
// r15/r17 kept 2 __syncthreads per tile (4 waves lock-step -> every wave's
// load window gated by the slowest wave). Here each wave owns a private 5KB
// LDS slice, stages its own 64 cells with 9 LINEAR 1KB loads, orders its own
// ds_write->ds_read via lgkmcnt (intra-wave, barrier-free is valid), computes,
// and free-runs to its next chunk. 16 waves/CU each hold ~9 loads in flight
// continuously with NO barrier coupling.
// Fragment layout (r5-verified): D = W1^T x x: col=cell=lane&15,
// row=h=(lane>>4)*4+reg. b1 folded into K row 36.
__global__ __launch_bounds__(256, 4) void mlp_kernel(
    const float* __restrict__ cell_state,
    const float* __restrict__ arch_state,
    const float* __restrict__ energy,
    const float* __restrict__ phi_local,
    const float* __restrict__ W1,
    const float* __restrict__ b1,
    const float* __restrict__ W2,
    const float* __restrict__ b2,
    float* __restrict__ w_out,
    int n)
{
    __shared__ _Float16 xs[4][64 * 40];  // 4 per-wave slices, 5120 B each
    __shared__ half8 wpack[8 * 64];      // 4 KB packed W1^T/b1 fragments
    const int tid  = threadIdx.x;
    const int lane = tid & 63;
    const int l15  = lane & 15;
    const int lg   = lane >> 4;          // 0..3
    const int wv   = tid >> 6;           // wave id in block, 0..3

    // ---- parallel pack: wave wv packs fragments f = 2*wv, 2*wv+1 ----
    #pragma unroll
    for (int fo = 0; fo < 2; ++fo) {
        const int f  = 2 * wv + fo;      // f = nt*2 + s
        const int nt = f >> 1;
        const int s  = f & 1;
        half8 v = {};
        #pragma unroll
        for (int jj = 0; jj < 8; ++jj) {
            const int k = 32 * s + lg * 8 + jj;
            float wvv = 0.0f;
            if (k < XDIM)       wvv = W1[k * HDIM + 16 * nt + l15];
            else if (k == XDIM) wvv = b1[16 * nt + l15];   // bias row
            v[jj] = (_Float16)wvv;
        }
        wpack[f * 64 + lane] = v;
    }
    __syncthreads();   // the ONLY block barrier in this kernel

    half8 af[4][2];
    #pragma unroll
    for (int nt = 0; nt < 4; ++nt)
        #pragma unroll
        for (int s = 0; s < 2; ++s)
            af[nt][s] = wpack[(nt * 2 + s) * 64 + lane];

    float w2v[16];
    #pragma unroll
    for (int nt = 0; nt < 4; ++nt)
        #pragma unroll
        for (int q = 0; q < 4; ++q)
            w2v[nt * 4 + q] = W2[16 * nt + lg * 4 + q];
    const float sb2 = b2[0];

    const float4* cell4 = reinterpret_cast<const float4*>(cell_state);
    const float4* arch4 = reinterpret_cast<const float4*>(arch_state);
    _Float16* myxs = xs[wv];

    const int nch  = (n + 63) >> 6;          // 64-cell chunks
    const int gwid = blockIdx.x * 4 + wv;    // global wave id
    const int nw   = gridDim.x * 4;

    #pragma unroll 1
    for (int ch = gwid; ch < nch; ch += nw) {
        const int cb = ch * 64;

        // ---- stage own 64 cells: 9 LINEAR 1KB loads/wave, cvt, ds_write ----
        #pragma unroll
        for (int uu = 0; uu < 8; ++uu) {
            const int u   = uu * 64 + lane;  // 512 float4 of this chunk
            const int row = u >> 3;
            const int c4  = u & 7;
            int gr = cb + row; if (gr >= n) gr = n - 1;
            const float4 v = cell4[(size_t)gr * 8 + c4];
            half4 h;
            h[0] = (_Float16)v.x; h[1] = (_Float16)v.y;
            h[2] = (_Float16)v.z; h[3] = (_Float16)v.w;
            *reinterpret_cast<half4*>(&myxs[row * 40 + c4 * 4]) = h;
        }
        {
            int gr = cb + lane; if (gr >= n) gr = n - 1;
            const float4 a = arch4[gr];
            half4 h;
            h[0] = (_Float16)a.x; h[1] = (_Float16)a.y;
            h[2] = (_Float16)a.z; h[3] = (_Float16)a.w;
            *reinterpret_cast<half4*>(&myxs[lane * 40 + 32]) = h;
            half4 hb;
            hb[0] = (_Float16)1.0f; hb[1] = (_Float16)0.0f;
            hb[2] = (_Float16)0.0f; hb[3] = (_Float16)0.0f;
            *reinterpret_cast<half4*>(&myxs[lane * 40 + 36]) = hb;
        }
        // no barrier: intra-wave ds_write -> ds_read ordered by lgkmcnt,
        // which the compiler inserts (same LDS object, provable dependence)

        // ---- compute: 4 tiles of 16 cells from own slice ----
        float acc = 0.0f;
        #pragma unroll
        for (int t = 0; t < 4; ++t) {
            const int r = 16 * t + l15;
            const half8 x0 = *reinterpret_cast<const half8*>(&myxs[r * 40 + lg * 8]);
            half8 x1 = {};
            if (lg == 0)
                x1 = *reinterpret_cast<const half8*>(&myxs[r * 40 + 32]);

            float pq = 0.0f;
            #pragma unroll
            for (int nt = 0; nt < 4; ++nt) {
                f32x4 cc = f32x4{0.f, 0.f, 0.f, 0.f};
                cc = __builtin_amdgcn_mfma_f32_16x16x32_f16(af[nt][0], x0, cc, 0, 0, 0);
                cc = __builtin_amdgcn_mfma_f32_16x16x32_f16(af[nt][1], x1, cc, 0, 0, 0);
                #pragma unroll
                for (int q = 0; q < 4; ++q)
                    pq = __builtin_fmaf(fmaxf(cc[q], 0.0f), w2v[nt * 4 + q], pq);
            }
            pq += __shfl_xor(pq, 16);
            pq += __shfl_xor(pq, 32);
            if (lg == t) acc = pq;
        }
        const float base = sigmoidf_(acc + sb2);

        const int gid = cb + lane;
        if (gid < n) {
            const float ep = energy[gid] * phi_local[gid];
            const float imp = fminf(fmaxf(base * ep, 0.01f), 1.0f);
            w_out[gid] = imp * ep;
        }
    }
}

// ---- one wave per cluster: plain-store partials (r15 proven-fast form) ----
__global__ __launch_bounds__(256) void cluster_kernel(
    const float* __restrict__ arch_state,
    const float* __restrict__ w_arr,
    const int*   __restrict__ startx,
    const int*   __restrict__ endx,
    const float* __restrict__ Wc1,
    const float* __restrict__ bc1,
    const float* __restrict__ Wc2,
    const float* __restrict__ bc2,
    float* __restrict__ out,
    float* __restrict__ ws2)
{
    const int lane = threadIdx.x & 63;
    const int c = blockIdx.x * 4 + (threadIdx.x >> 6);
    const int s0 = startx[c];
    const int e0 = endx[c];

    float pw = 0.0f;
    float pa0 = 0.f, pa1 = 0.f, pa2 = 0.f, pa3 = 0.f;
    float pw0 = 0.f, pw1 = 0.f, pw2 = 0.f, pw3 = 0.f;
    float pq0 = 0.f, pq1 = 0.f, pq2 = 0.f, pq3 = 0.f;
    const float4* arch4 = reinterpret_cast<const float4*>(arch_state);

    int i = s0 + lane;
    bool vcur = i < e0;
    float4 ac = {}; float wcur = 0.0f;
    if (vcur) { ac = arch4[i]; wcur = w_arr[i]; }
    while (vcur) {
        const int j = i + 64;
        const bool vnext = j < e0;
        float4 an = {}; float wnext = 0.0f;
        if (vnext) { an = arch4[j]; wnext = w_arr[j]; }   // prefetch next
        pw += wcur;
        pa0 += ac.x; pa1 += ac.y; pa2 += ac.z; pa3 += ac.w;
        pw0 = __builtin_fmaf(wcur, ac.x, pw0); pw1 = __builtin_fmaf(wcur, ac.y, pw1);
        pw2 = __builtin_fmaf(wcur, ac.z, pw2); pw3 = __builtin_fmaf(wcur, ac.w, pw3);
        pq0 = __builtin_fmaf(ac.x, ac.x, pq0); pq1 = __builtin_fmaf(ac.y, ac.y, pq1);
        pq2 = __builtin_fmaf(ac.z, ac.z, pq2); pq3 = __builtin_fmaf(ac.w, ac.w, pq3);
        i = j; vcur = vnext; ac = an; wcur = wnext;
    }
#define RED13(F) F(pw) F(pa0) F(pa1) F(pa2) F(pa3) \
                 F(pw0) F(pw1) F(pw2) F(pw3) F(pq0) F(pq1) F(pq2) F(pq3)
#define BFLY(V) V += __shfl_xor(V, off_);
    #pragma unroll
    for (int off_ = 1; off_ < 64; off_ <<= 1) { RED13(BFLY) }

    const float cnt = (float)(e0 - s0);
    const float safe_cnt = fmaxf(cnt, 1.0f);
    const float wsum = pw;

    float agg[4];
    if (wsum > 0.0f) {
        const float inv = 1.0f / fmaxf(wsum, 1e-30f);
        agg[0] = pw0 * inv; agg[1] = pw1 * inv;
        agg[2] = pw2 * inv; agg[3] = pw3 * inv;
    } else {
        const float inv = 1.0f / safe_cnt;
        agg[0] = pa0 * inv; agg[1] = pa1 * inv;
        agg[2] = pa2 * inv; agg[3] = pa3 * inv;
    }

    const float sA[4]  = { pa0, pa1, pa2, pa3 };
    const float sA2[4] = { pq0, pq1, pq2, pq3 };
    float sq = 0.0f;
    #pragma unroll
    for (int d = 0; d < 4; ++d) {
        const float mean = sA[d] / safe_cnt;
        const float s2 = sA2[d] - 2.0f * mean * sA[d] + cnt * mean * mean;
        sq += fmaxf(s2, 0.0f);
    }
    const float var = (cnt >= 2.0f) ? (sq * 0.25f) / fmaxf(cnt - 1.0f, 1.0f) : 0.0f;
    const float phi_c = 1.0f - fminf(1.0f, var * 2.0f);
    const float coh = 1.0f - var;

    const float feats[7] = { agg[0], agg[1], agg[2], agg[3],
                             phi_c, coh, fminf(1.0f, cnt * 0.05f) };
    float t = bc2[0];
    #pragma unroll
    for (int j = 0; j < 32; ++j) {
        float hj = bc1[j];
        #pragma unroll
        for (int k = 0; k < 7; ++k)
            hj = __builtin_fmaf(feats[k], Wc1[k * 32 + j], hj);
        t += fmaxf(hj, 0.0f) * Wc2[j];
    }
    const float basec = sigmoidf_(t);
    const float impc = fminf(fmaxf(basec * phi_c, 0.01f), 1.0f);
    const bool valid = cnt > 0.0f;
    const float wc = valid ? impc * cnt : 0.0f;
    const float vf = valid ? 1.0f : 0.0f;

    if (lane == 0) {
        out[c * 4 + 0] = agg[0]; out[c * 4 + 1] = agg[1];
        out[c * 4 + 2] = agg[2]; out[c * 4 + 3] = agg[3];
        out[NC * 4 + c] = phi_c;
        out[NC * 5 + c] = coh;
        ws2[0 * NC + c] = wc;
        ws2[1 * NC + c] = vf;
        #pragma unroll
        for (int d = 0; d < 4; ++d) ws2[(2 + d) * NC + c] = wc * agg[d];
        #pragma unroll
        for (int d = 0; d < 4; ++d) ws2[(6 + d) * NC + c] = vf * agg[d];
    }
}

// ---- single-block reduction of the 10 per-cluster partial arrays ----
__global__ __launch_bounds__(1024) void finalize_kernel(
    const float* __restrict__ ws2, float* __restrict__ out)
{
    __shared__ float red[16][10];
    const int tid = threadIdx.x;
    const int lane = tid & 63;
    const int wv = tid >> 6;

    float r[10];
    #pragma unroll
    for (int k = 0; k < 10; ++k) r[k] = 0.0f;
    for (int c = tid; c < NC; c += 1024) {
        #pragma unroll
        for (int k = 0; k < 10; ++k) r[k] += ws2[k * NC + c];
    }
    #pragma unroll
    for (int off = 1; off < 64; off <<= 1) {
        #pragma unroll
        for (int k = 0; k < 10; ++k) r[k] += __shfl_xor(r[k], off);
    }
    if (lane == 0) {
        #pragma unroll
        for (int k = 0; k < 10; ++k) red[wv][k] = r[k];
    }
    __syncthreads();
    if (tid == 0) {
        float g[10];
        #pragma unroll
        for (int k = 0; k < 10; ++k) {
            float acc = 0.0f;
            for (int i = 0; i < 16; ++i) acc += red[i][k];
            g[k] = acc;
        }
        const float wcs = g[0];
        const float nv = fmaxf(g[1], 1.0f);
        #pragma unroll
        for (int d = 0; d < 4; ++d) {
            out[NC * 6 + d] = (wcs > 0.0f) ? g[2 + d] / fmaxf(wcs, 1e-30f)
                                           : g[6 + d] / nv;
        }
    }
}

extern "C" void kernel_launch(void* const* d_in, const int* in_sizes, int n_in,
                              void* d_out, int out_size, void* d_ws, size_t ws_size,
                              hipStream_t stream) {
    const float* cell_state = (const float*)d_in[0];
    const float* arch_state = (const float*)d_in[1];
    const float* energy     = (const float*)d_in[2];
    const float* phi_local  = (const float*)d_in[3];
    const float* W1  = (const float*)d_in[4];
    const float* b1  = (const float*)d_in[5];
    const float* W2  = (const float*)d_in[6];
    const float* b2  = (const float*)d_in[7];
    const float* Wc1 = (const float*)d_in[8];
    const float* bc1 = (const float*)d_in[9];
    const float* Wc2 = (const float*)d_in[10];
    const float* bc2 = (const float*)d_in[11];
    const int* seg   = (const int*)d_in[12];

    const int n = in_sizes[2];  // energy is [N]
    float* out = (float*)d_out;

    float* w_arr = (float*)d_ws;                  // n floats
    int* startx  = (int*)(w_arr + n);             // NC ints
    int* endx    = startx + NC;                   // NC ints
    float* ws2   = (float*)(endx + NC);           // 10*NC floats

    bounds_kernel<<<(n + 255) / 256, 256, 0, stream>>>(seg, startx, endx, n);
    mlp_kernel<<<MLP_BLOCKS, 256, 0, stream>>>(cell_state, arch_state, energy,
                                               phi_local, W1, b1, W2, b2,
                                               w_arr, n);
    cluster_kernel<<<NC / 4, 256, 0, stream>>>(arch_state, w_arr, startx, endx,
                                               Wc1, bc1, Wc2, bc2, out, ws2);
    finalize_kernel<<<1, 1024, 0, stream>>>(ws2, out);
}